// Round 6
// baseline (84.968 us; speedup 1.0000x reference)
//
#include <hip/hip_runtime.h>
#include <math.h>

#define N_ROWS 8192
#define N_NEG 16
#define NBLK (N_ROWS / 8)   // 1024 main-kernel blocks
#define NEG_INF (-3.0e38f)

__device__ __forceinline__ float log_sigmoid(float v) {
    // log(sigmoid(v)) = min(v,0) - log1p(exp(-|v|))  (numerically stable)
    return fminf(v, 0.0f) - log1pf(__expf(-fabsf(v)));
}

__device__ __forceinline__ float wave_max64(float v) {
    v = fmaxf(v, __shfl_xor(v, 1));
    v = fmaxf(v, __shfl_xor(v, 2));
    v = fmaxf(v, __shfl_xor(v, 4));
    v = fmaxf(v, __shfl_xor(v, 8));
    v = fmaxf(v, __shfl_xor(v, 16));
    v = fmaxf(v, __shfl_xor(v, 32));
    return v;
}

// Per-lane sorted-descending top-5 insert, branch-free, 5 VALU ops.
// For sorted t0>=..>=t4: new t_k = med3(c, t_{k-1}, t_k) is exactly the
// sorted-insert shift; new t0 = max(t0, c). Ties/duplicates are fine.
#define INS5(cexpr)                                                     \
    {                                                                   \
        const float _c = (cexpr);                                       \
        const float n0 = fmaxf(t0, _c);                                 \
        const float n1 = __builtin_amdgcn_fmed3f(_c, t0, t1);           \
        const float n2 = __builtin_amdgcn_fmed3f(_c, t1, t2);           \
        const float n3 = __builtin_amdgcn_fmed3f(_c, t2, t3);           \
        const float n4 = __builtin_amdgcn_fmed3f(_c, t3, t4);           \
        t0 = n0; t1 = n1; t2 = n2; t3 = n3; t4 = n4;                    \
    }

// 8 waves/block, one row per wave. Scan phase is pure VALU (zero
// cross-lane, zero branches); merge phase does 16 wave-max selection
// rounds; rare exact fallback for the <6-per-lane exactness hole.
__global__ __launch_bounds__(512, 8) void nsl_topk_kernel(
        const float* __restrict__ x,
        const int*   __restrict__ sel,
        float*       __restrict__ ws) {
    __shared__ int   sel_lds[N_ROWS];
    __shared__ float partial[8];

    // cooperative stage of the full sel vector (32 KB), coalesced int4
    {
        const int4* s4 = reinterpret_cast<const int4*>(sel);
        int4*       d4 = reinterpret_cast<int4*>(sel_lds);
#pragma unroll
        for (int k = 0; k < 4; ++k)
            d4[k * 512 + threadIdx.x] = s4[k * 512 + threadIdx.x];
    }
    __syncthreads();

    const int lane = threadIdx.x & 63;
    const int wid  = threadIdx.x >> 6;
    const int row  = (blockIdx.x << 3) + wid;

    const int    seli = sel_lds[row];
    const float* xrow = x + (size_t)row * N_ROWS;
    const float* pw   = xrow + (lane << 2);

    float t0 = NEG_INF, t1 = NEG_INF, t2 = NEG_INF, t3 = NEG_INF, t4 = NEG_INF;

    // batch c = floats [c*256 .. c*256+255]; lane owns one float4.
#define LOADB(c) (*reinterpret_cast<const float4*>(pw + ((c) << 8)))
#define CONSUME(c, bx, PF)                                              \
    {                                                                   \
        const float4 v = bx;                                            \
        if (PF) bx = LOADB((c) + 4);                                    \
        const int4 s = *reinterpret_cast<const int4*>(                  \
            &sel_lds[((c) << 8) + (lane << 2)]);                        \
        INS5((s.x != seli) ? v.x : 0.0f);                               \
        INS5((s.y != seli) ? v.y : 0.0f);                               \
        INS5((s.z != seli) ? v.z : 0.0f);                               \
        INS5((s.w != seli) ? v.w : 0.0f);                               \
    }

    float4 b0 = LOADB(0), b1 = LOADB(1), b2 = LOADB(2), b3 = LOADB(3);

#pragma unroll 1
    for (int g = 0; g < 7; ++g) {
        const int c = g << 2;
        CONSUME(c + 0, b0, true);
        CONSUME(c + 1, b1, true);
        CONSUME(c + 2, b2, true);
        CONSUME(c + 3, b3, true);
    }
    CONSUME(28, b0, false);   // tail: no prefetch, no wrap reloads
    CONSUME(29, b1, false);
    CONSUME(30, b2, false);
    CONSUME(31, b3, false);
#undef CONSUME

    // ---- merge: 16 selection rounds over the 64x5 = 320 candidates ----
    const float t4_orig = t4;      // lane's 5th-largest (watermark)
    float negsum = 0.0f;           // wave-uniform accumulation
    float tau16  = 0.0f;
#pragma unroll 1
    for (int r = 0; r < 16; ++r) {
        const float h = wave_max64(t0);
        negsum += log_sigmoid(-h);
        tau16 = h;
        const unsigned long long b = __ballot(t0 == h);
        if (lane == (__ffsll(b) - 1)) {           // pop exactly one holder
            t0 = t1; t1 = t2; t2 = t3; t3 = t4; t4 = NEG_INF;
        }
    }

    // ---- exactness fallback (P ~ 3e-4 per row): if some lane's 5th
    // value exceeds tau16 it may have discarded a top-16 member.
    // Exact distributed-insert rescan of this row (wave-uniform branch).
    if (__any(t4_orig > tau16)) {
        float dt = NEG_INF, tau = NEG_INF;  // sorted list in lanes 0..15
#pragma unroll 1
        for (int c = 0; c < 32; ++c) {
            const float4 v = LOADB(c);
            const int4 s = *reinterpret_cast<const int4*>(
                &sel_lds[(c << 8) + (lane << 2)]);
            float m[4];
            m[0] = (s.x != seli) ? v.x : 0.0f;
            m[1] = (s.y != seli) ? v.y : 0.0f;
            m[2] = (s.z != seli) ? v.z : 0.0f;
            m[3] = (s.w != seli) ? v.w : 0.0f;
#pragma unroll
            for (int k = 0; k < 4; ++k) {
                unsigned long long ball = __ballot(m[k] > tau);
                while (ball) {
                    const int src = __ffsll(ball) - 1;
                    const float cand = __shfl(m[k], src);
                    ball &= ball - 1;
                    if (cand > tau) {
                        float tprev = __shfl_up(dt, 1);
                        if (lane == 0) tprev = 3.0e38f;
                        dt = (dt >= cand) ? dt : (tprev >= cand ? cand : tprev);
                        tau = __shfl(dt, 15);
                        ball &= __ballot(m[k] > tau);
                    }
                }
            }
        }
        float ls = (lane < 16) ? log_sigmoid(-dt) : 0.0f;
        ls += __shfl_xor(ls, 8);
        ls += __shfl_xor(ls, 4);
        ls += __shfl_xor(ls, 2);
        ls += __shfl_xor(ls, 1);
        negsum = ls;               // only lane 0's value is consumed below
    }
#undef LOADB

    if (lane == 0) {
        const float d = xrow[row];                  // raw diagonal score
        partial[wid] = -log_sigmoid(d) * (1.0f / (float)N_ROWS)
                       - negsum * (1.0f / ((float)N_ROWS * (float)N_NEG));
    }
    __syncthreads();

    if (threadIdx.x == 0) {
        float s = 0.0f;
#pragma unroll
        for (int w = 0; w < 8; ++w) s += partial[w];
        ws[blockIdx.x] = s;                         // plain store, no atomic
    }
}

// single-block final reduce: 1024 partials -> d_out[0]
__global__ __launch_bounds__(256) void nsl_reduce_kernel(
        const float* __restrict__ ws, float* __restrict__ out) {
    __shared__ float red[4];
    float s = 0.0f;
#pragma unroll
    for (int k = 0; k < NBLK / 256; ++k) s += ws[k * 256 + threadIdx.x];
    s += __shfl_xor(s, 32);
    s += __shfl_xor(s, 16);
    s += __shfl_xor(s, 8);
    s += __shfl_xor(s, 4);
    s += __shfl_xor(s, 2);
    s += __shfl_xor(s, 1);
    const int lane = threadIdx.x & 63, wid = threadIdx.x >> 6;
    if (lane == 0) red[wid] = s;
    __syncthreads();
    if (threadIdx.x == 0)
        out[0] = red[0] + red[1] + red[2] + red[3];
}

extern "C" void kernel_launch(void* const* d_in, const int* in_sizes, int n_in,
                              void* d_out, int out_size, void* d_ws, size_t ws_size,
                              hipStream_t stream) {
    const float* x   = (const float*)d_in[0];
    const int*   sel = (const int*)d_in[1];
    float* out = (float*)d_out;
    float* ws  = (float*)d_ws;

    nsl_topk_kernel<<<dim3(NBLK), dim3(512), 0, stream>>>(x, sel, ws);
    nsl_reduce_kernel<<<dim3(1), dim3(256), 0, stream>>>(ws, out);
}